// Round 21
// baseline (101.331 us; speedup 1.0000x reference)
//
#include <hip/hip_runtime.h>

#define HH 512
#define IND 13
#define NN 2048
#define RR 256
#define WDIM 7168      // (13+1)*512
#define W1DIM 6656     // 13*512
#define NBLK 256       // n per block (4 waves x 64 n, nt=4)
#define NTHREADS 256
#define XPK_BYTES (NN * 32 * 2)            // 131072 B: packed x
#define WPK_SHORTS_PER_R 9216              // 512*16 w1 shorts + 1024 shorts (512 f32 w2)
#define WPK_BYTES (RR * WPK_SHORTS_PER_R * 2)  // 4718592 B
#define NEG_HALF_LOG_2PI (-0.91893853320467274f)

typedef __attribute__((ext_vector_type(8))) short short8;   // 8 bf16 (4 VGPRs) MFMA A/B frag
typedef __attribute__((ext_vector_type(4))) float f32x4;    // MFMA C/D frag
typedef __attribute__((ext_vector_type(2))) float f32x2;    // packed-math pair

// fp32 -> bf16 round-to-nearest-even (bit pattern) -- used for w1 (error-dominant term)
__device__ __forceinline__ short f2bf(float f) {
    unsigned u = __float_as_uint(f);
    u += 0x7fffu + ((u >> 16) & 1u);
    return (short)(u >> 16);
}

// R21: kill the per-block prologue+barrier entirely (R20 post-mortem: issue
// floor ~7us vs ~39us measured, invariant across occupancy/nt/block-count =>
// the shared factor is the serial staging chain + __syncthreads). wprep
// writes the exact per-r LDS image [512 x 16-short bf16 w1 | 512 f32 w2]
// into d_ws once (vs 8x/r in-block); the main kernel reads A-frags and w2
// quads straight from L2 (r-fast grid keeps wpk[r] in one XCD's L2), has
// NO LDS, NO barrier, NO conversions. MFMA inputs bit-identical to R20.
// Ledger: relu-split BANNED (R3/R4/R15); divergent partial short8 writes
// BANNED (R11/R12); branch-free builds, direct relu, 256 thr = proven-green.

__global__ __launch_bounds__(NTHREADS)
void xprep_kernel(const float* __restrict__ x, short* __restrict__ xpk) {
    const int n = blockIdx.x * NTHREADS + threadIdx.x;   // grid covers 2048 rows
    const float* xp = x + (size_t)n * IND;
    short tmp[32];
#pragma unroll
    for (int i = 0; i < 13; ++i) {
        float v = xp[i];
        unsigned u = __float_as_uint(v);
        tmp[i] = (short)(u >> 16);                         // hi: truncate to bf16
        float res = v - __uint_as_float(u & 0xffff0000u);  // exact remainder
        tmp[16 + i] = (short)(__float_as_uint(res) >> 16); // lo: truncate remainder
    }
    tmp[13] = 0; tmp[14] = 0; tmp[15] = 0;
    tmp[29] = 0; tmp[30] = 0; tmp[31] = 0;
    short8* dst = (short8*)(xpk + (size_t)n * 32);
    dst[0] = *(short8*)&tmp[0];
    dst[1] = *(short8*)&tmp[8];
    dst[2] = *(short8*)&tmp[16];
    dst[3] = *(short8*)&tmp[24];
}

// per-r weight image: w1 rows [w1(13)|0(3)] bf16 (8192 shorts) then w2 f32 (2048 B)
__global__ __launch_bounds__(NTHREADS)
void wprep_kernel(const float* __restrict__ w, short* __restrict__ wpk) {
    const int r = blockIdx.x;
    const int tid = threadIdx.x;
    const float* wr = w + (size_t)r * WDIM;
    short* dst = wpk + (size_t)r * WPK_SHORTS_PER_R;
#pragma unroll
    for (int rr = 0; rr < 2; ++rr) {
        const int h = tid * 2 + rr;
        const float* p = wr + (size_t)h * IND;
        short tmp[16];
#pragma unroll
        for (int i = 0; i < 13; ++i) tmp[i] = f2bf(p[i]);
        tmp[13] = 0; tmp[14] = 0; tmp[15] = 0;
        *(short8*)&dst[h * 16]     = *(short8*)&tmp[0];
        *(short8*)&dst[h * 16 + 8] = *(short8*)&tmp[8];
    }
    float* w2d = (float*)(dst + HH * 16);
    w2d[tid]       = wr[W1DIM + tid];
    w2d[tid + 256] = wr[W1DIM + tid + 256];
}

// main: LDS-free, barrier-free; weights + x read from prepacked L2-hot images
__global__ __launch_bounds__(NTHREADS)
void ffrelu_l2_kernel(const float* __restrict__ y,
                      const short* __restrict__ wpk,
                      const short* __restrict__ xpk,
                      float* __restrict__ out) {
    const int tid = threadIdx.x;
    const int r = blockIdx.x;       // fast dim: same-r blocks -> same XCD
    const int wave = tid >> 6;
    const int lane = tid & 63;
    const int m = lane & 15;        // MFMA row/col index within 16
    const int q = lane >> 4;        // quad 0..3

    const short* wr1 = wpk + (size_t)r * WPK_SHORTS_PER_R;
    const float* w2p = (const float*)(wr1 + HH * 16);

    const bool lo  = (q >= 2);     // q2/q3 lanes carry x_lo
    const bool hi8 = (q & 1);      // q1/q3 lanes carry slice [8..12]
    const f32x2 zero2 = {0.0f, 0.0f};
    const f32x4 czero = {0.0f, 0.0f, 0.0f, 0.0f};

    // ---- 4 B-frags (64 n per wave), one aligned 16B load each ----
    const int nb = blockIdx.y * NBLK + wave * 64;
    const short* xbase = xpk + (size_t)(nb + m) * 32 + (lo ? 16 : 0) + (hi8 ? 8 : 0);
    short8 bfrag[4];
#pragma unroll
    for (int nt = 0; nt < 4; ++nt) {
        bfrag[nt] = *(const short8*)(xbase + nt * 16 * 32);
    }

    f32x2 muv[4][2];
#pragma unroll
    for (int i = 0; i < 4; ++i) {
        muv[i][0] = zero2;
        muv[i][1] = zero2;
    }

    // ---- main loop: 32 h-tiles x 4 n-tiles; A + w2 straight from L2 ----
#pragma unroll 2
    for (int t = 0; t < 32; ++t) {
        const short8 a = *(const short8*)&wr1[(t * 16 + m) * 16 + (q & 1) * 8];
        const f32x4 wv = *(const f32x4*)&w2p[t * 16 + q * 4];
        const f32x2 wv01 = {wv[0], wv[1]};
        const f32x2 wv23 = {wv[2], wv[3]};
#pragma unroll
        for (int nt = 0; nt < 4; ++nt) {
            f32x4 c = __builtin_amdgcn_mfma_f32_16x16x32_bf16(a, bfrag[nt], czero, 0, 0, 0);
            // C layout: col n = lane&15, row h = t*16 + q*4 + reg
            f32x2 c01 = {c[0], c[1]};
            f32x2 c23 = {c[2], c[3]};
            c01 = __builtin_elementwise_max(c01, zero2);
            c23 = __builtin_elementwise_max(c23, zero2);
            muv[nt][0] += c01 * wv01;    // v_pk_fma_f32
            muv[nt][1] += c23 * wv23;
        }
    }

    // ---- horizontal sum + quad butterfly ----
    float mu[4];
#pragma unroll
    for (int nt = 0; nt < 4; ++nt) {
        f32x2 p = muv[nt][0] + muv[nt][1];
        float v = p[0] + p[1];
        v += __shfl_xor(v, 16, 64);
        v += __shfl_xor(v, 32, 64);
        mu[nt] = v;
    }

    float mu0;
    if (q == 0)      mu0 = mu[0];
    else if (q == 1) mu0 = mu[1];
    else if (q == 2) mu0 = mu[2];
    else             mu0 = mu[3];

    const int n0 = nb + lane;
    float resid0 = y[n0] - mu0;
    out[(size_t)r * NN + n0] = fmaf(-0.5f * resid0, resid0, NEG_HALF_LOG_2PI);
}

// fallback (ws too small): R20-style self-contained kernel (LDS staging +
// in-kernel branch-free truncation build)
__global__ __launch_bounds__(NTHREADS, 3)
void ffrelu_fallback_kernel(const float* __restrict__ x,
                            const float* __restrict__ y,
                            const float* __restrict__ w,
                            float* __restrict__ out) {
    __shared__ short Als[HH * 16];
    __shared__ float w2s[HH];

    const int tid = threadIdx.x;
    const int r = blockIdx.x;
    const int wave = tid >> 6;
    const int lane = tid & 63;
    const int m = lane & 15;
    const int q = lane >> 4;

    const float* wr = w + (size_t)r * WDIM;

#pragma unroll
    for (int rr = 0; rr < 2; ++rr) {
        const int h = tid * 2 + rr;
        const float* p = wr + (size_t)h * IND;
        short tmp[16];
#pragma unroll
        for (int i = 0; i < 13; ++i) tmp[i] = f2bf(p[i]);
        tmp[13] = 0; tmp[14] = 0; tmp[15] = 0;
        *(short8*)&Als[h * 16]     = *(short8*)&tmp[0];
        *(short8*)&Als[h * 16 + 8] = *(short8*)&tmp[8];
    }
    w2s[tid]       = wr[W1DIM + tid];
    w2s[tid + 256] = wr[W1DIM + tid + 256];
    __syncthreads();

    const bool lo  = (q >= 2);
    const bool hi8 = (q & 1);
    const f32x2 zero2 = {0.0f, 0.0f};
    const f32x4 czero = {0.0f, 0.0f, 0.0f, 0.0f};

    const int nb = blockIdx.y * NBLK + wave * 64;
    short8 bfrag[4];
#pragma unroll
    for (int nt = 0; nt < 4; ++nt) {
        const float* xp = x + (size_t)(nb + nt * 16 + m) * IND;
        short hs[13], ls[13];
#pragma unroll
        for (int i = 0; i < 13; ++i) {
            float v = xp[i];
            unsigned u = __float_as_uint(v);
            hs[i] = (short)(u >> 16);
            float res = v - __uint_as_float(u & 0xffff0000u);
            ls[i] = (short)(__float_as_uint(res) >> 16);
        }
        short s[13];
#pragma unroll
        for (int i = 0; i < 13; ++i) s[i] = lo ? ls[i] : hs[i];
        short8 b;
        b[0] = hi8 ? s[8]     : s[0];
        b[1] = hi8 ? s[9]     : s[1];
        b[2] = hi8 ? s[10]    : s[2];
        b[3] = hi8 ? s[11]    : s[3];
        b[4] = hi8 ? s[12]    : s[4];
        b[5] = hi8 ? (short)0 : s[5];
        b[6] = hi8 ? (short)0 : s[6];
        b[7] = hi8 ? (short)0 : s[7];
        bfrag[nt] = b;
    }

    f32x2 muv[4][2];
#pragma unroll
    for (int i = 0; i < 4; ++i) {
        muv[i][0] = zero2;
        muv[i][1] = zero2;
    }

#pragma unroll 2
    for (int t = 0; t < 32; ++t) {
        const short8 a = *(const short8*)&Als[(t * 16 + m) * 16 + (q & 1) * 8];
        const f32x4 wv = *(const f32x4*)&w2s[t * 16 + q * 4];
        const f32x2 wv01 = {wv[0], wv[1]};
        const f32x2 wv23 = {wv[2], wv[3]};
#pragma unroll
        for (int nt = 0; nt < 4; ++nt) {
            f32x4 c = __builtin_amdgcn_mfma_f32_16x16x32_bf16(a, bfrag[nt], czero, 0, 0, 0);
            f32x2 c01 = {c[0], c[1]};
            f32x2 c23 = {c[2], c[3]};
            c01 = __builtin_elementwise_max(c01, zero2);
            c23 = __builtin_elementwise_max(c23, zero2);
            muv[nt][0] += c01 * wv01;
            muv[nt][1] += c23 * wv23;
        }
    }

    float mu[4];
#pragma unroll
    for (int nt = 0; nt < 4; ++nt) {
        f32x2 p = muv[nt][0] + muv[nt][1];
        float v = p[0] + p[1];
        v += __shfl_xor(v, 16, 64);
        v += __shfl_xor(v, 32, 64);
        mu[nt] = v;
    }

    float mu0;
    if (q == 0)      mu0 = mu[0];
    else if (q == 1) mu0 = mu[1];
    else if (q == 2) mu0 = mu[2];
    else             mu0 = mu[3];

    const int n0 = nb + lane;
    float resid0 = y[n0] - mu0;
    out[(size_t)r * NN + n0] = fmaf(-0.5f * resid0, resid0, NEG_HALF_LOG_2PI);
}

extern "C" void kernel_launch(void* const* d_in, const int* in_sizes, int n_in,
                              void* d_out, int out_size, void* d_ws, size_t ws_size,
                              hipStream_t stream) {
    const float* x = (const float*)d_in[0];   // [N, 13]
    const float* y = (const float*)d_in[1];   // [N, 1]
    const float* w = (const float*)d_in[2];   // [R, 7168]
    float* out = (float*)d_out;               // [R, N]

    dim3 grid(RR, NN / NBLK);   // (256, 8): r fast -> same-r blocks share an XCD
    dim3 block(NTHREADS);

    if (ws_size >= (size_t)(XPK_BYTES + WPK_BYTES)) {
        short* xpk = (short*)d_ws;                          // [N, 32]
        short* wpk = (short*)((char*)d_ws + XPK_BYTES);     // [R, 9216]
        xprep_kernel<<<NN / NTHREADS, NTHREADS, 0, stream>>>(x, xpk);
        wprep_kernel<<<RR, NTHREADS, 0, stream>>>(w, wpk);
        ffrelu_l2_kernel<<<grid, block, 0, stream>>>(y, wpk, xpk, out);
    } else {
        ffrelu_fallback_kernel<<<grid, block, 0, stream>>>(x, y, w, out);
    }
}